// Round 7
// baseline (574.414 us; speedup 1.0000x reference)
//
#include <hip/hip_runtime.h>

#define ALPHA 0.2f

typedef float f4 __attribute__((ext_vector_type(4)));

// lane i <- lane i-1 (shfl_up by 1), lane 0 <- 0   [DPP wave_shr:1, bound_ctrl 0-fill]
__device__ __forceinline__ float dpp_up1(float x) {
  return __builtin_bit_cast(float, __builtin_amdgcn_update_dpp(
      0, __builtin_bit_cast(int, x), 0x138, 0xf, 0xf, true));
}
// lane i <- lane i+1 (shfl_down by 1), lane 63 <- 0 [DPP wave_shl:1]
__device__ __forceinline__ float dpp_dn1(float x) {
  return __builtin_bit_cast(float, __builtin_amdgcn_update_dpp(
      0, __builtin_bit_cast(int, x), 0x130, 0xf, 0xf, true));
}

__device__ __forceinline__ float leaky_f(float x) { return fmaxf(x, ALPHA * x); }

// Fused 10-iteration Jacobi stencil, one wave per (plane, 128-row strip).
// Lane l owns columns 4l..4l+3 (full 256-wide coverage -> no horizontal halo;
// horizontal neighbor exchange via DPP with 0-fill == zero padding).
//
// Partial-sum line pipeline: each stage k keeps TWO vertical partial sums
// (pend0 = w1*h(p-1)+h(p), pend1 = w1*h(p)) of the horizontally-filtered row
// stream h, instead of a 3-row raw window -> 80 floats of pipeline state.
// amdgpu_waves_per_eu(2,2) pins the allocator to a 256-VGPR budget so the
// state stays in ARCH VGPRs (round-4 showed launch_bounds(64,2) alone leaves
// it at 72 VGPR + acc-shuttle). o rows live in a 12-deep wave-private LDS
// ring (no barriers). Sweep r = y0-10 .. y0+139 (150 steps).
__global__ __launch_bounds__(64)
__attribute__((amdgpu_waves_per_eu(2, 2)))
void pipe_k(
    const float* __restrict__ o,
    const float* __restrict__ nb_sigma,
    const float* __restrict__ lam,
    float* __restrict__ out)
{
  __shared__ float ring[12][256];

  const int lane  = threadIdx.x;      // 0..63
  const int x4    = lane << 2;        // first owned column
  const int bid   = blockIdx.x;       // 0..2047
  const int strip = bid & 1;
  const int plane = bid >> 1;         // b*64 + c
  const int c     = plane & 63;
  const int y0    = strip << 7;       // 0 or 128
  const int start = y0 - 10;

  const float sig  = nb_sigma[c];
  const float sig2 = sig * sig;
  const float w1   = expf(-0.5f / sig2);                        // per-axis off-center weight
  const float s    = lam[0] / (0.62831853071795864769f * sig2); // lam / (0.2*pi*sigma^2)

  const float* __restrict__ pb = o   + ((size_t)plane << 16);
  float* __restrict__       ob = out + ((size_t)plane << 16);

  // per-stage vertical partial sums of the h-filtered stream
  f4 pend0[10], pend1[10];
#pragma unroll
  for (int k = 0; k < 10; ++k) {
    pend0[k] = (f4)0.0f;
    pend1[k] = (f4)0.0f;
  }

  auto ldrow = [&](int r) -> f4 {
    int rr = r < 0 ? 0 : (r > 255 ? 255 : r);   // clamped (values unused when OOB)
    return *reinterpret_cast<const f4*>(pb + (rr << 8) + x4);
  };

  f4 ocur  = ldrow(start);       // o(row r) for current step
  f4 onext = ldrow(start + 1);   // depth-2 prefetch
  int bslot = 0;                 // ring slot of row r  (= t mod 12)

#pragma unroll 1
  for (int t = 0; t < 150; ++t) {
    const int r = start + t;

    f4 onn = ldrow(r + 2);       // prefetch 2 ahead

    // stage o(r) into the ring (read by stages 1..10 over the next 10 steps)
    *reinterpret_cast<f4*>(&ring[bslot][x4]) = ocur;

    // v_0(r) = 1 - 2*leaky(o(r)); rows outside the image are zero (uniform SALU selects)
    const bool in0 = (r >= 0) & (r <= 255);
    const float m0 = in0 ? -2.0f : 0.0f;
    const float c0 = in0 ?  1.0f : 0.0f;
    f4 w;                        // row-stream value cascading down the stages
    w.x = fmaf(m0, leaky_f(ocur.x), c0);
    w.y = fmaf(m0, leaky_f(ocur.y), c0);
    w.z = fmaf(m0, leaky_f(ocur.z), c0);
    w.w = fmaf(m0, leaky_f(ocur.w), c0);

    int sk = bslot;              // will walk back to slot (t-k) mod 12
#pragma unroll
    for (int k = 1; k <= 10; ++k) {
      sk = (sk == 0) ? 11 : sk - 1;

      // horizontal pass on arriving row w (row r-k+1 of iterate k-1)
      const float hl = dpp_up1(w.w);   // column 4l-1 from lane l-1 (0-fill at edge)
      const float hr = dpp_dn1(w.x);   // column 4l+4 from lane l+1
      f4 h;
      h.x = fmaf(w1, hl  + w.y, w.x);
      h.y = fmaf(w1, w.x + w.z, w.y);
      h.z = fmaf(w1, w.y + w.w, w.z);
      h.w = fmaf(w1, w.z + hr , w.w);

      // complete vertical sum for row r-k: g = pend0 + w1*h
      f4 g;
      g.x = fmaf(w1, h.x, pend0[k-1].x);
      g.y = fmaf(w1, h.y, pend0[k-1].y);
      g.z = fmaf(w1, h.z, pend0[k-1].z);
      g.w = fmaf(w1, h.w, pend0[k-1].w);
      // roll partial sums
      pend0[k-1].x = pend1[k-1].x + h.x;
      pend0[k-1].y = pend1[k-1].y + h.y;
      pend0[k-1].z = pend1[k-1].z + h.z;
      pend0[k-1].w = pend1[k-1].w + h.w;
      pend1[k-1].x = w1 * h.x;
      pend1[k-1].y = w1 * h.y;
      pend1[k-1].z = w1 * h.z;
      pend1[k-1].w = w1 * h.w;

      // o(r-k) from the LDS ring
      const f4 ok = *reinterpret_cast<const f4*>(&ring[sk][x4]);

      // u = leaky(o - s*g)
      f4 u;
      u.x = leaky_f(fmaf(-s, g.x, ok.x));
      u.y = leaky_f(fmaf(-s, g.y, ok.y));
      u.z = leaky_f(fmaf(-s, g.z, ok.z));
      u.w = leaky_f(fmaf(-s, g.w, ok.w));

      const int rho = r - k;
      if (k < 10) {
        // v_k(rho) = 1 - 2u, zero outside the image (uniform selects)
        const bool in = (rho >= 0) & (rho <= 255);
        const float mm = in ? -2.0f : 0.0f;
        const float cc = in ?  1.0f : 0.0f;
        w.x = fmaf(mm, u.x, cc);
        w.y = fmaf(mm, u.y, cc);
        w.z = fmaf(mm, u.z, cc);
        w.w = fmaf(mm, u.w, cc);
      } else {
        // iterate 10 == final u: store rows owned by this strip
        if (rho >= y0 && rho < y0 + 128) {
          __builtin_nontemporal_store(u, reinterpret_cast<f4*>(ob + (rho << 8) + x4));
        }
      }
    }

    ocur  = onext;
    onext = onn;
    bslot = (bslot == 11) ? 0 : bslot + 1;
  }
}

extern "C" void kernel_launch(void* const* d_in, const int* in_sizes, int n_in,
                              void* d_out, int out_size, void* d_ws, size_t ws_size,
                              hipStream_t stream)
{
  const float* o        = (const float*)d_in[0];
  const float* nb_sigma = (const float*)d_in[1];
  const float* lam      = (const float*)d_in[2];
  float* out = (float*)d_out;

  // 1024 planes x 2 row-strips (128 rows), one 64-thread (1-wave) block each
  pipe_k<<<dim3(2048), dim3(64), 0, stream>>>(o, nb_sigma, lam, out);
}